// Round 5
// baseline (6266.254 us; speedup 1.0000x reference)
//
#include <hip/hip_runtime.h>

// EnhancedQuantumInspiredLSTM on MI355X (gfx950).
// Round-5: merged-layer persistent kernel. 32 WGs, each owns 16 h-cols of
// BOTH LSTM layers (lag-1 pipeline: epoch tau = l0 step tau + l1 step tau-1).
// hs1 eliminated (l1 x-proj consumes the staged h0 tile directly). Dual-phase
// flags (flag0 mid-epoch after h0 publish, flag1 at end) keep the epoch
// critical path on l0 only. Wave0-only polling, per-WG 256B flag lines.
// q-tile prefetched one epoch ahead via global_load_lds (swizzle inverted on
// the global address side; LDS side is wave-uniform base + lane*16).

typedef _Float16 f16;
typedef _Float16 f16x8 __attribute__((ext_vector_type(8)));
typedef float f32x4 __attribute__((ext_vector_type(4)));
typedef unsigned long long u64;

#define MFMA16(a, b, c) __builtin_amdgcn_mfma_f32_16x16x32_f16((a), (b), (c), 0, 0, 0)

// ---- workspace layout (bytes) ----
#define OFF_Q16 0UL           // 32768*512*2 = 33,554,432
#define OFF_X16 33554432UL    // 32768*128*2 = 8,388,608
#define OFF_W16 41943040UL    // 4*2048*512*2 = 8,388,608  [l][ih,hh]
#define OFF_COS 50331648UL    // 131,072 (transposed [h][i])
#define OFF_SIN 50462720UL    // 131,072
#define OFF_BSUM 50593792UL   // 16,384
#define OFF_HBUF 50610176UL   // 2*2*64*512*2 = 262,144 [layer][slot][b][j]
#define OFF_HLAST 50872320UL  // 131,072
#define OFF_FC1WT 51003392UL  // 1,048,576
#define OFF_FLG 52051968UL    // 16,384 (flags0: 32x256B, flags1 at +8KB)
#define WS_NEEDED 52068352UL

// =====================================================================
// prep
// =====================================================================
__global__ __launch_bounds__(256) void k_prep(
    const float* __restrict__ x, const float* __restrict__ theta,
    const float* __restrict__ phi, const float* __restrict__ thn,
    const float* __restrict__ phn, const float* __restrict__ Wih,
    const float* __restrict__ Whh, const float* __restrict__ bih,
    const float* __restrict__ bhh, const float* __restrict__ fc1w,
    f16* __restrict__ x16, f16* __restrict__ w16, f16* __restrict__ cosT,
    f16* __restrict__ sinT, float* __restrict__ bsum, float* __restrict__ fc1wT,
    f16* __restrict__ hbuf, unsigned* __restrict__ flags) {
  const int T1 = 4194304;
  const int T2 = T1 + 4194304;
  const int T3 = T2 + 65536;
  const int T4 = T3 + 262144;
  const int T5 = T4 + 4096;
  const int T6 = T5 + 131072;
  const int T7 = T6 + 4096;
  for (int idx = blockIdx.x * 256 + threadIdx.x; idx < T7; idx += gridDim.x * 256) {
    if (idx < T1) {
      int s = idx >> 13, rem = idx & 8191, b = rem >> 7, i = rem & 127;
      x16[idx] = (f16)x[b * 65536 + s * 128 + i];
    } else if (idx < T2) {
      int j = idx - T1;
      if (j < 2097152) {
        int l = j >> 20, r = j & 1048575;
        w16[(size_t)(l * 2 + 0) * 1048576 + r] = (f16)Wih[j];
      } else {
        int j2 = j - 2097152;
        int l = j2 >> 20, r = j2 & 1048575;
        w16[(size_t)(l * 2 + 1) * 1048576 + r] = (f16)Whh[j2];
      }
    } else if (idx < T3) {
      int e = idx - T2;
      int i = e >> 9, h = e & 511;
      cosT[h * 128 + i] = (f16)cosf(theta[e] + thn[e]);
      sinT[h * 128 + i] = (f16)sinf(phi[e] + phn[e]);
    } else if (idx < T4) {
      int e = idx - T3;
      int n = e >> 9, k = e & 511;
      fc1wT[k * 512 + n] = fc1w[e];
    } else if (idx < T5) {
      int e = idx - T4;
      bsum[e] = bih[e] + bhh[e];
    } else if (idx < T6) {
      hbuf[idx - T5] = (f16)0.f;
    } else {
      flags[idx - T6] = 0u;
    }
  }
}

// =====================================================================
// quantum: q16[(s*64+b)][h] = |x.(cos+isin)|, fp16 MFMA
// =====================================================================
__global__ __launch_bounds__(256) void k_quantum(
    const f16* __restrict__ x16, const f16* __restrict__ cosT,
    const f16* __restrict__ sinT, f16* __restrict__ q16) {
  __shared__ __align__(16) f16 a_lds[64 * 136];
  const int tid = threadIdx.x;
  const int r0 = blockIdx.x * 64, h0 = blockIdx.y * 128;
#pragma unroll
  for (int g = 0; g < 4; ++g) {
    int G = g * 256 + tid, row = G >> 4, col = G & 15;
    *(uint4*)((char*)a_lds + row * 272 + col * 16) =
        *(const uint4*)(x16 + (size_t)(r0 + row) * 128 + col * 8);
  }
  __syncthreads();
  const int wv = tid >> 6, lane = tid & 63, n15 = lane & 15, quad = lane >> 4;
  const int nb = h0 + wv * 32;
  f32x4 ac[4][2], as_[4][2];
#pragma unroll
  for (int mt = 0; mt < 4; ++mt)
#pragma unroll
    for (int nt = 0; nt < 2; ++nt) {
      ac[mt][nt] = (f32x4){0.f, 0.f, 0.f, 0.f};
      as_[mt][nt] = (f32x4){0.f, 0.f, 0.f, 0.f};
    }
#pragma unroll
  for (int it = 0; it < 4; ++it) {
    f16x8 a[4];
#pragma unroll
    for (int mt = 0; mt < 4; ++mt)
      a[mt] = *(const f16x8*)((const char*)a_lds + (mt * 16 + n15) * 272 + it * 64 + quad * 16);
#pragma unroll
    for (int nt = 0; nt < 2; ++nt) {
      const f16x8 bc = *(const f16x8*)(cosT + (size_t)(nb + nt * 16 + n15) * 128 + it * 32 + quad * 8);
      const f16x8 bs = *(const f16x8*)(sinT + (size_t)(nb + nt * 16 + n15) * 128 + it * 32 + quad * 8);
#pragma unroll
      for (int mt = 0; mt < 4; ++mt) {
        ac[mt][nt] = MFMA16(a[mt], bc, ac[mt][nt]);
        as_[mt][nt] = MFMA16(a[mt], bs, as_[mt][nt]);
      }
    }
  }
#pragma unroll
  for (int mt = 0; mt < 4; ++mt)
#pragma unroll
    for (int nt = 0; nt < 2; ++nt)
#pragma unroll
      for (int r = 0; r < 4; ++r) {
        int row = r0 + mt * 16 + quad * 4 + r;
        int col = nb + nt * 16 + n15;
        float re = ac[mt][nt][r], im = as_[mt][nt][r];
        q16[(size_t)row * 512 + col] = (f16)sqrtf(re * re + im * im);
      }
}

// =====================================================================
// recurrent persistent kernel helpers
// =====================================================================
// async global->LDS q prefetch; swizzle (c ^ (row&7)) inverted on global side
__device__ __forceinline__ void prefetch_q_lds(f16* qstage, const f16* src, int tid) {
#pragma unroll
  for (int i = 0; i < 8; ++i) {
    int slot = i * 512 + tid;
    int row = slot >> 6, g = slot & 63;
    int gs = g ^ (row & 7);
    const f16* gp = src + (size_t)row * 512 + gs * 8;
    f16* lp = qstage + (size_t)slot * 8;
    __builtin_amdgcn_global_load_lds(
        (const __attribute__((address_space(1))) unsigned int*)gp,
        (__attribute__((address_space(3))) unsigned int*)lp, 16, 0, 0);
  }
}
__device__ __forceinline__ void issue_coh(u64* r, const f16* __restrict__ src, int tid) {
#pragma unroll
  for (int i = 0; i < 8; ++i) {
    const u64* p = (const u64*)(src + (size_t)(i * 512 + tid) * 8);
    r[2 * i] = __hip_atomic_load(p, __ATOMIC_RELAXED, __HIP_MEMORY_SCOPE_AGENT);
    r[2 * i + 1] = __hip_atomic_load(p + 1, __ATOMIC_RELAXED, __HIP_MEMORY_SCOPE_AGENT);
  }
}
__device__ __forceinline__ void commit_stage(f16* stage, const u64* r, int tid) {
#pragma unroll
  for (int i = 0; i < 8; ++i) {
    int G = i * 512 + tid;
    int row = G >> 6, c = G & 63;
    char* d = (char*)stage + row * 1024 + ((c ^ (row & 7)) * 16);
    *(u64*)d = r[2 * i];
    *(u64*)(d + 8) = r[2 * i + 1];
  }
}
__device__ __forceinline__ f16x8 lds_a(const f16* stage, int row, int it, int quad) {
  int g = (it * 4 + quad) ^ (row & 7);
  return *(const f16x8*)((const char*)stage + row * 1024 + g * 16);
}
__device__ __forceinline__ float sigf(float x) { return 1.f / (1.f + __expf(-x)); }
__device__ __forceinline__ float tanhf_fast(float x) { return 1.f - 2.f / (__expf(2.f * x) + 1.f); }

// =====================================================================
// k_rec: 32 WGs x 512 threads. Waves 0-3: layer 0 (gate wv&3); 4-7: layer 1.
// =====================================================================
__global__ __launch_bounds__(512, 2) void k_rec(
    const f16* __restrict__ q16, const f16* __restrict__ w16,
    const float* __restrict__ bsum, f16* __restrict__ hbuf,
    float* __restrict__ hlast, unsigned* flags) {
  extern __shared__ __align__(16) char smem[];  // 131072 B dynamic
  f16* qstage = (f16*)smem;             // 64 KB: q tile (prefetched)
  f16* hstage = (f16*)(smem + 65536);   // 64 KB: h0 tile, then h1 tile
  float* gbuf = (float*)(smem + 65536); // overlay on hstage, pitch 68

  const int tid = threadIdx.x, lane = tid & 63, wv = tid >> 6;
  const int lw = wv >> 2, qg = wv & 3;  // lw: layer role, qg: gate (i,f,g,o)
  const int c0 = blockIdx.x * 16;       // h-col slice
  const int n15 = lane & 15, quad = lane >> 4;

  // resident weights for this wave's layer: Wih/Whh rows [qg*512+c0 .. +16)
  f16x8 wih[16], whh[16];
  {
    const f16* base = w16 + (size_t)(lw * 2) * 1048576 +
                      (size_t)(qg * 512 + c0 + n15) * 512 + quad * 8;
#pragma unroll
    for (int it = 0; it < 16; ++it) {
      wih[it] = *(const f16x8*)(base + it * 32);
      whh[it] = *(const f16x8*)(base + 1048576 + it * 32);
    }
  }
  const int eb = tid >> 3, ejc = (tid & 7) * 2;
  float bb[2][4][2];
#pragma unroll
  for (int l = 0; l < 2; ++l)
#pragma unroll
    for (int g = 0; g < 4; ++g)
#pragma unroll
      for (int j = 0; j < 2; ++j)
        bb[l][g][j] = bsum[l * 2048 + g * 512 + c0 + ejc + j];
  float cs[2][2] = {{0.f, 0.f}, {0.f, 0.f}};

  unsigned* flags0 = flags;
  unsigned* flags1 = flags + 2048;  // +8 KB
  const unsigned* fp0 = flags0 + (size_t)(lane & 31) * 64;
  const unsigned* fp1 = flags1 + (size_t)(lane & 31) * 64;

  prefetch_q_lds(qstage, q16, tid);  // q[0]
  __syncthreads();                   // drains vmcnt; qstage ready

  for (int tau = 0; tau <= 512; ++tau) {
    const bool act0 = (tau <= 511);  // l0 step tau
    const bool act1 = (tau >= 1);    // l1 step tau-1
    f32x4 acc[4];
#pragma unroll
    for (int m = 0; m < 4; ++m) acc[m] = (f32x4){0.f, 0.f, 0.f, 0.f};

    // P1: l0 x-projection (q tile), overlapped with wave0's flags0 poll
    if (lw == 0 && act0) {
#pragma unroll
      for (int it = 0; it < 16; ++it)
#pragma unroll
        for (int m = 0; m < 4; ++m)
          acc[m] = MFMA16(lds_a(qstage, m * 16 + n15, it, quad), wih[it], acc[m]);
    }
    if (wv == 0 && tau >= 1) {
      const unsigned tgt = (unsigned)tau;
      while (true) {
        unsigned f = __hip_atomic_load(fp0, __ATOMIC_RELAXED, __HIP_MEMORY_SCOPE_AGENT);
        if (__all((int)(f >= tgt))) break;
      }
    }
    __syncthreads();  // B1: qstage reads done + h0(tau-1) available

    // P2: prefetch q[tau+1] (lands async; next consumed after many barriers)
    if (tau + 1 <= 511)
      prefetch_q_lds(qstage, q16 + (size_t)(tau + 1) * 32768, tid);

    // P3: stage h0(tau-1) (coherent; slot tau&1)
    u64 hr[16];
    issue_coh(hr, hbuf + (size_t)(0 * 2 + (tau & 1)) * 32768, tid);
    commit_stage(hstage, hr, tid);
    __syncthreads();  // B2: hstage = h0(tau-1)

    // P4: recurrent GEMM l0 + x-projection l1 (both read hstage)
    if (lw == 0) {
      if (act0) {
#pragma unroll
        for (int it = 0; it < 16; ++it)
#pragma unroll
          for (int m = 0; m < 4; ++m)
            acc[m] = MFMA16(lds_a(hstage, m * 16 + n15, it, quad), whh[it], acc[m]);
      }
    } else {
      if (act1) {
#pragma unroll
        for (int it = 0; it < 16; ++it)
#pragma unroll
          for (int m = 0; m < 4; ++m)
            acc[m] = MFMA16(lds_a(hstage, m * 16 + n15, it, quad), wih[it], acc[m]);
      }
    }
    if (wv == 0 && tau >= 2) {  // h1(tau-2) published with flag1 == tau
      const unsigned tgt = (unsigned)tau;
      while (true) {
        unsigned f = __hip_atomic_load(fp1, __ATOMIC_RELAXED, __HIP_MEMORY_SCOPE_AGENT);
        if (__all((int)(f >= tgt))) break;
      }
    }
    __syncthreads();  // B3: hstage reads done + h1(tau-2) available

    // P5: issue h1(tau-2) loads early (slot (tau-1)&1); latency hides under l0 tail
    if (act1)
      issue_coh(hr, hbuf + (size_t)(2 + ((tau - 1) & 1)) * 32768, tid);

    // P6: l0 gate pre-acts -> gbuf (hstage overlay)
    if (lw == 0 && act0) {
#pragma unroll
      for (int m = 0; m < 4; ++m)
#pragma unroll
        for (int r = 0; r < 4; ++r)
          gbuf[(m * 16 + quad * 4 + r) * 68 + qg * 16 + n15] = acc[m][r];
    }
    __syncthreads();  // B4: gbuf ready

    // P7: l0 elementwise + publish h0(tau) (slot (tau+1)&1)
    if (act0) {
      float hv[2];
#pragma unroll
      for (int j = 0; j < 2; ++j) {
        const float* gb = gbuf + eb * 68 + ejc + j;
        float gi = gb[0] + bb[0][0][j];
        float gf = gb[16] + bb[0][1][j];
        float gg = gb[32] + bb[0][2][j];
        float go = gb[48] + bb[0][3][j];
        float c = sigf(gf) * cs[0][j] + sigf(gi) * tanhf_fast(gg);
        cs[0][j] = c;
        hv[j] = sigf(go) * tanhf_fast(c);
      }
      union { f16 h2[2]; unsigned u; } pk;
      pk.h2[0] = (f16)hv[0];
      pk.h2[1] = (f16)hv[1];
      unsigned* hb = (unsigned*)(hbuf + (size_t)(0 * 2 + ((tau + 1) & 1)) * 32768 +
                                 eb * 512 + c0 + ejc);
      __hip_atomic_store(hb, pk.u, __ATOMIC_RELAXED, __HIP_MEMORY_SCOPE_AGENT);
    }
    __syncthreads();  // B5: drain (h0 stores visible; h1 loads returned; gbuf done)
    if (tid == 0 && act0)
      __hip_atomic_store(&flags0[(size_t)blockIdx.x * 64], (unsigned)(tau + 1),
                         __ATOMIC_RELAXED, __HIP_MEMORY_SCOPE_AGENT);

    // P8: commit h1(tau-2) -> hstage (overwrites h0 tile + gbuf; safe after B5)
    if (act1) commit_stage(hstage, hr, tid);
    __syncthreads();  // B6: hstage = h1(tau-2)

    // P9: l1 recurrent GEMM
    if (lw == 1 && act1) {
#pragma unroll
      for (int it = 0; it < 16; ++it)
#pragma unroll
        for (int m = 0; m < 4; ++m)
          acc[m] = MFMA16(lds_a(hstage, m * 16 + n15, it, quad), whh[it], acc[m]);
    }
    __syncthreads();  // B7: hstage reads done

    // P10: l1 gate pre-acts -> gbuf
    if (lw == 1 && act1) {
#pragma unroll
      for (int m = 0; m < 4; ++m)
#pragma unroll
        for (int r = 0; r < 4; ++r)
          gbuf[(m * 16 + quad * 4 + r) * 68 + qg * 16 + n15] = acc[m][r];
    }
    __syncthreads();  // B8: gbuf ready

    // P11: l1 elementwise + publish h1(tau-1) (slot tau&1); hlast at step 511
    if (act1) {
      float hv[2];
#pragma unroll
      for (int j = 0; j < 2; ++j) {
        const float* gb = gbuf + eb * 68 + ejc + j;
        float gi = gb[0] + bb[1][0][j];
        float gf = gb[16] + bb[1][1][j];
        float gg = gb[32] + bb[1][2][j];
        float go = gb[48] + bb[1][3][j];
        float c = sigf(gf) * cs[1][j] + sigf(gi) * tanhf_fast(gg);
        cs[1][j] = c;
        hv[j] = sigf(go) * tanhf_fast(c);
      }
      union { f16 h2[2]; unsigned u; } pk;
      pk.h2[0] = (f16)hv[0];
      pk.h2[1] = (f16)hv[1];
      unsigned* hb = (unsigned*)(hbuf + (size_t)(2 + (tau & 1)) * 32768 +
                                 eb * 512 + c0 + ejc);
      __hip_atomic_store(hb, pk.u, __ATOMIC_RELAXED, __HIP_MEMORY_SCOPE_AGENT);
      if (tau == 512) {
        hlast[eb * 512 + c0 + ejc] = hv[0];
        hlast[eb * 512 + c0 + ejc + 1] = hv[1];
      }
    }
    __syncthreads();  // B9: drain h1 stores
    if (tid == 0 && act1 && tau <= 511)
      __hip_atomic_store(&flags1[(size_t)blockIdx.x * 64], (unsigned)(tau + 1),
                         __ATOMIC_RELAXED, __HIP_MEMORY_SCOPE_AGENT);
  }
}

// =====================================================================
// fc head
// =====================================================================
__global__ __launch_bounds__(512) void k_fc(
    const float* __restrict__ hlast, const float* __restrict__ fc1wT,
    const float* __restrict__ fc1b, const float* __restrict__ fc2w,
    const float* __restrict__ fc2b, float* __restrict__ out) {
  __shared__ float hrow[512];
  __shared__ float red[8];
  const int b = blockIdx.x, tid = threadIdx.x;
  hrow[tid] = hlast[b * 512 + tid];
  __syncthreads();
  float acc = 0.f;
#pragma unroll 8
  for (int k = 0; k < 512; ++k) acc += hrow[k] * fc1wT[k * 512 + tid];
  float h1 = acc + fc1b[tid];
  h1 = h1 > 0.f ? h1 : 0.f;
  float v = h1 * fc2w[tid];
#pragma unroll
  for (int off = 32; off >= 1; off >>= 1) v += __shfl_down(v, off);
  if ((tid & 63) == 0) red[tid >> 6] = v;
  __syncthreads();
  if (tid == 0) {
    float s = 0.f;
#pragma unroll
    for (int w = 0; w < 8; ++w) s += red[w];
    out[b] = s + fc2b[0];
  }
}

// =====================================================================
extern "C" void kernel_launch(void* const* d_in, const int* in_sizes, int n_in,
                              void* d_out, int out_size, void* d_ws, size_t ws_size,
                              hipStream_t stream) {
  if (ws_size < WS_NEEDED) return;  // fail loudly

  const float* x = (const float*)d_in[0];
  const float* theta = (const float*)d_in[1];
  const float* phi = (const float*)d_in[2];
  const float* thn = (const float*)d_in[3];
  const float* phn = (const float*)d_in[4];
  const float* Wih = (const float*)d_in[5];
  const float* Whh = (const float*)d_in[6];
  const float* bih = (const float*)d_in[7];
  const float* bhh = (const float*)d_in[8];
  const float* fc1w = (const float*)d_in[9];
  const float* fc1b = (const float*)d_in[10];
  const float* fc2w = (const float*)d_in[11];
  const float* fc2b = (const float*)d_in[12];

  char* ws = (char*)d_ws;
  f16* q16 = (f16*)(ws + OFF_Q16);
  f16* x16 = (f16*)(ws + OFF_X16);
  f16* w16 = (f16*)(ws + OFF_W16);
  f16* cosT = (f16*)(ws + OFF_COS);
  f16* sinT = (f16*)(ws + OFF_SIN);
  float* bsum = (float*)(ws + OFF_BSUM);
  f16* hbuf = (f16*)(ws + OFF_HBUF);
  float* hlast = (float*)(ws + OFF_HLAST);
  float* fc1wT = (float*)(ws + OFF_FC1WT);
  unsigned* flags = (unsigned*)(ws + OFF_FLG);

  static bool attr_set = false;  // host-side only
  if (!attr_set) {
    hipFuncSetAttribute((const void*)k_rec,
                        hipFuncAttributeMaxDynamicSharedMemorySize, 131072);
    attr_set = true;
  }

  k_prep<<<2048, 256, 0, stream>>>(x, theta, phi, thn, phn, Wih, Whh, bih, bhh, fc1w,
                                   x16, w16, cosT, sinT, bsum, fc1wT, hbuf, flags);
  k_quantum<<<dim3(512, 4, 1), 256, 0, stream>>>(x16, cosT, sinT, q16);
  k_rec<<<32, 512, 131072, stream>>>(q16, w16, bsum, hbuf, hlast, flags);
  k_fc<<<64, 512, 0, stream>>>(hlast, fc1wT, fc1b, fc2w, fc2b, (float*)d_out);
}

// Round 8
// 1853.428 us; speedup vs baseline: 3.3809x; 3.3809x over previous
//
#include <hip/hip_runtime.h>

// EnhancedQuantumInspiredLSTM on MI355X (gfx950).
// Round-8 = round-7 structure with the layer-1 timestep off-by-one fixed:
// l1 step t consumes h0(t) (slot t&3, poll f0>=t+1), matching the reference
// h1(t)=Cell(x=h0(t), h=h1(t-1)). r7 fed h0(t-1) -> absmax 0.111.
//  - 4 batch domains x 16 rows; each domain syncs only its own 32 WGs.
//  - per WG: one fused K=1024 MFMA GEMM (A=[x|h], B=[Wih|Whh]), M=16 full.
//  - l0 critical loop: own flags + WAR guard f1>=t-2 (4 h0 slots).
//  - sync: AGENT relaxed atomics, __syncthreads vmcnt-drain before publish.

typedef _Float16 f16;
typedef _Float16 f16x8 __attribute__((ext_vector_type(8)));
typedef float f32x4 __attribute__((ext_vector_type(4)));
typedef unsigned long long u64;

#define MFMA16(a, b, c) __builtin_amdgcn_mfma_f32_16x16x32_f16((a), (b), (c), 0, 0, 0)
#define LD_AG(p) __hip_atomic_load((p), __ATOMIC_RELAXED, __HIP_MEMORY_SCOPE_AGENT)
#define ST_AG(p, v) __hip_atomic_store((p), (v), __ATOMIC_RELAXED, __HIP_MEMORY_SCOPE_AGENT)

// ---- workspace layout (bytes) ----
#define OFF_Q16 0UL           // 32768*512*2 = 33,554,432  rows = s*64+b
#define OFF_X16 33554432UL    // 8,388,608
#define OFF_W16 41943040UL    // 2*2048*1024*2 = 8,388,608  [l][row][k']
#define OFF_COS 50331648UL    // 131,072 (transposed [h][i])
#define OFF_SIN 50462720UL    // 131,072
#define OFF_BSUM 50593792UL   // 16,384
#define OFF_HBUF 50610176UL   // h0 4dom*4slot*16*512*2=262,144 ; h1 4*2*16*512*2=131,072
#define OFF_HLAST 51003392UL  // 131,072
#define OFF_FC1WT 51134464UL  // 1,048,576
#define OFF_FLG 52183040UL    // 128 flags * 256B = 32,768
#define WS_NEEDED 52215808UL

// =====================================================================
// prep
// =====================================================================
__global__ __launch_bounds__(256) void k_prep(
    const float* __restrict__ x, const float* __restrict__ theta,
    const float* __restrict__ phi, const float* __restrict__ thn,
    const float* __restrict__ phn, const float* __restrict__ Wih,
    const float* __restrict__ Whh, const float* __restrict__ bih,
    const float* __restrict__ bhh, const float* __restrict__ fc1w,
    f16* __restrict__ x16, f16* __restrict__ w16, f16* __restrict__ cosT,
    f16* __restrict__ sinT, float* __restrict__ bsum, float* __restrict__ fc1wT,
    f16* __restrict__ hbuf, unsigned* __restrict__ flg) {
  const int T1 = 4194304;        // x16
  const int T2 = T1 + 4194304;   // w16 combined [l][2048][1024]
  const int T3 = T2 + 65536;     // cos/sin
  const int T4 = T3 + 262144;    // fc1wT
  const int T5 = T4 + 4096;      // bsum
  const int T6 = T5 + 196608;    // zero hbuf (h0+h1, f16 count)
  const int T7 = T6 + 8192;      // zero flags (dwords)
  for (int idx = blockIdx.x * 256 + threadIdx.x; idx < T7; idx += gridDim.x * 256) {
    if (idx < T1) {
      int s = idx >> 13, rem = idx & 8191, b = rem >> 7, i = rem & 127;
      x16[idx] = (f16)x[b * 65536 + s * 128 + i];
    } else if (idx < T2) {
      int j = idx - T1;
      int l = j >> 21, rem = j & 2097151, r = rem >> 10, k = rem & 1023;
      float v = (k < 512) ? Wih[((size_t)l * 2048 + r) * 512 + k]
                          : Whh[((size_t)l * 2048 + r) * 512 + (k - 512)];
      w16[(size_t)l * 2097152 + (size_t)r * 1024 + k] = (f16)v;
    } else if (idx < T3) {
      int e = idx - T2;
      int i = e >> 9, h = e & 511;
      cosT[h * 128 + i] = (f16)cosf(theta[e] + thn[e]);
      sinT[h * 128 + i] = (f16)sinf(phi[e] + phn[e]);
    } else if (idx < T4) {
      int e = idx - T3;
      int n = e >> 9, k = e & 511;
      fc1wT[k * 512 + n] = fc1w[e];
    } else if (idx < T5) {
      int e = idx - T4;
      bsum[e] = bih[e] + bhh[e];
    } else if (idx < T6) {
      hbuf[idx - T5] = (f16)0.f;
    } else {
      flg[idx - T6] = 0u;
    }
  }
}

// =====================================================================
// quantum: q16[(s*64+b)][h] = |x.(cos+isin)|, fp16 MFMA (unchanged)
// =====================================================================
__global__ __launch_bounds__(256) void k_quantum(
    const f16* __restrict__ x16, const f16* __restrict__ cosT,
    const f16* __restrict__ sinT, f16* __restrict__ q16) {
  __shared__ __align__(16) f16 a_lds[64 * 136];
  const int tid = threadIdx.x;
  const int r0 = blockIdx.x * 64, h0 = blockIdx.y * 128;
#pragma unroll
  for (int g = 0; g < 4; ++g) {
    int G = g * 256 + tid, row = G >> 4, col = G & 15;
    *(uint4*)((char*)a_lds + row * 272 + col * 16) =
        *(const uint4*)(x16 + (size_t)(r0 + row) * 128 + col * 8);
  }
  __syncthreads();
  const int wv = tid >> 6, lane = tid & 63, n15 = lane & 15, quad = lane >> 4;
  const int nb = h0 + wv * 32;
  f32x4 ac[4][2], as_[4][2];
#pragma unroll
  for (int mt = 0; mt < 4; ++mt)
#pragma unroll
    for (int nt = 0; nt < 2; ++nt) {
      ac[mt][nt] = (f32x4){0.f, 0.f, 0.f, 0.f};
      as_[mt][nt] = (f32x4){0.f, 0.f, 0.f, 0.f};
    }
#pragma unroll
  for (int it = 0; it < 4; ++it) {
    f16x8 a[4];
#pragma unroll
    for (int mt = 0; mt < 4; ++mt)
      a[mt] = *(const f16x8*)((const char*)a_lds + (mt * 16 + n15) * 272 + it * 64 + quad * 16);
#pragma unroll
    for (int nt = 0; nt < 2; ++nt) {
      const f16x8 bc = *(const f16x8*)(cosT + (size_t)(nb + nt * 16 + n15) * 128 + it * 32 + quad * 8);
      const f16x8 bs = *(const f16x8*)(sinT + (size_t)(nb + nt * 16 + n15) * 128 + it * 32 + quad * 8);
#pragma unroll
      for (int mt = 0; mt < 4; ++mt) {
        ac[mt][nt] = MFMA16(a[mt], bc, ac[mt][nt]);
        as_[mt][nt] = MFMA16(a[mt], bs, as_[mt][nt]);
      }
    }
  }
#pragma unroll
  for (int mt = 0; mt < 4; ++mt)
#pragma unroll
    for (int nt = 0; nt < 2; ++nt)
#pragma unroll
      for (int r = 0; r < 4; ++r) {
        int row = r0 + mt * 16 + quad * 4 + r;
        int col = nb + nt * 16 + n15;
        float re = ac[mt][nt][r], im = as_[mt][nt][r];
        q16[(size_t)row * 512 + col] = (f16)sqrtf(re * re + im * im);
      }
}

// =====================================================================
// k_rec helpers
// =====================================================================
__device__ __forceinline__ f16x8 lds_a(const char* astage, int row, int it, int quad) {
  int pos = (it * 4 + quad) ^ (row & 7);  // XOR swizzle on low-3 granule bits
  return *(const f16x8*)(astage + row * 2048 + pos * 16);
}
__device__ __forceinline__ float sigf(float x) { return 1.f / (1.f + __expf(-x)); }
__device__ __forceinline__ float tanhf_fast(float x) { return 1.f - 2.f / (__expf(2.f * x) + 1.f); }

// =====================================================================
// k_rec: 128 WGs x 512 thr. dom=blockIdx>>5 (16 batch rows), role=blockIdx&31:
// roles 0-15 layer0 (32 h-cols each), 16-31 layer1. Per step t:
//   l0: A=[q(t)|h0(t-1)], publish h0(t) slot t&3, flag f0=t+1
//   l1: A=[h0(t)|h1(t-1)], publish h1(t) slot t&1, flag f1=t+1
// Polls: l0: f0>=t && f1>=t-2 (WAR guard); l1: f0>=t+1 && f1>=t.
// =====================================================================
__global__ __launch_bounds__(512, 2) void k_rec(
    const f16* __restrict__ q16, const f16* __restrict__ w16,
    const float* __restrict__ bsum, f16* __restrict__ h0buf,
    f16* __restrict__ h1buf, float* __restrict__ hlast, unsigned* flg) {
  __shared__ __align__(16) char astage[32768];  // 16 rows x 1024 f16
  __shared__ float gbuf[16 * 132];

  const int tid = threadIdx.x, lane = tid & 63, wv = tid >> 6;
  const int n15 = lane & 15, quad = lane >> 4;
  const int qg = wv >> 1, ch = wv & 1;  // gate, col-half for this wave
  const int dom = blockIdx.x >> 5, role = blockIdx.x & 31;
  const int l = role >> 4, c0 = (role & 15) * 32;
  const int b0 = dom * 16;

  // resident combined weights: rows qg*512 + c0 + ch*16 + n15, K'=1024
  f16x8 wf[32];
  {
    const f16* wbase = w16 + ((size_t)l * 2048 + (size_t)(qg * 512 + c0 + ch * 16 + n15)) * 1024 + quad * 8;
#pragma unroll
    for (int it = 0; it < 32; ++it) wf[it] = *(const f16x8*)(wbase + it * 32);
  }
  float bb[4][2];  // used by ew threads (tid<256): b=tid>>4, jc=(tid&15)*2
#pragma unroll
  for (int g = 0; g < 4; ++g)
#pragma unroll
    for (int j = 0; j < 2; ++j)
      bb[g][j] = bsum[l * 2048 + g * 512 + c0 + (tid & 15) * 2 + j];
  float cs0 = 0.f, cs1 = 0.f;

  // flags: [dom][layer][16 producers], 256B (64-dword) stride
  unsigned* f0 = flg + (size_t)(dom * 2 + 0) * 1024;
  unsigned* f1 = flg + (size_t)(dom * 2 + 1) * 1024;
  unsigned* myflag = (l ? f1 : f0) + (size_t)(role & 15) * 64;
  const int pl = lane & 31;
  const unsigned* pollp = (pl < 16) ? (f0 + pl * 64) : (f1 + (pl - 16) * 64);

  // staging: thread -> row=tid>>5 (16), colgrp=tid&31 (32 x 16 f16 = 32B)
  const int srow = tid >> 5, scg = tid & 31;
  const int g0 = scg * 2;
  char* a_x0 = astage + srow * 2048 + ((g0 ^ (srow & 7)) * 16);
  char* a_x1 = astage + srow * 2048 + (((g0 + 1) ^ (srow & 7)) * 16);
  char* a_h0 = a_x0 + 1024;  // granule +64 (low-3 XOR unaffected)
  char* a_h1 = a_x1 + 1024;
  const size_t soff = (size_t)srow * 512 + scg * 16;  // within a 16x512 slot
  const size_t h0base = (size_t)dom * 4 * 8192;
  const size_t h1base = (size_t)dom * 2 * 8192;

  for (int t = 0; t <= 511; ++t) {
    // stage x-part for l0 (immutable q, plain cached loads)
    if (l == 0) {
      const f16* src = q16 + ((size_t)(t * 64 + b0 + srow)) * 512 + scg * 16;
      uint4 v0 = *(const uint4*)src;
      uint4 v1 = *(const uint4*)(src + 8);
      *(uint4*)a_x0 = v0;
      *(uint4*)a_x1 = v1;
    }
    // poll (every wave; one lane-parallel load per iteration)
    // l0: f0>=t (peers at t-1 done), f1>=t-2 (WAR: l1 done reading slot t&3)
    // l1: f0>=t+1 (h0(t) published), f1>=t (peers' h1(t-1) published)
    if (t >= 1 || l == 1) {
      const int mytgt = (l == 0) ? ((pl < 16) ? t : (t - 2))
                                 : ((pl < 16) ? (t + 1) : t);
      while (true) {
        int f = (int)LD_AG(pollp);
        if (__all(f >= mytgt)) break;
        __builtin_amdgcn_s_sleep(1);
      }
    }
    // stage h-part(s) (AGENT coherent loads)
    if (l == 0) {
      const u64* hs0 = (const u64*)(h0buf + h0base + (size_t)((t - 1) & 3) * 8192 + soff);
      u64 x0 = LD_AG(hs0);
      u64 x1 = LD_AG(hs0 + 1);
      u64 x2 = LD_AG(hs0 + 2);
      u64 x3 = LD_AG(hs0 + 3);
      ((u64*)a_h0)[0] = x0; ((u64*)a_h0)[1] = x1;
      ((u64*)a_h1)[0] = x2; ((u64*)a_h1)[1] = x3;
    } else {
      const u64* hs0 = (const u64*)(h0buf + h0base + (size_t)(t & 3) * 8192 + soff);  // h0(t)
      u64 x0 = LD_AG(hs0);
      u64 x1 = LD_AG(hs0 + 1);
      u64 x2 = LD_AG(hs0 + 2);
      u64 x3 = LD_AG(hs0 + 3);
      const u64* hs1 = (const u64*)(h1buf + h1base + (size_t)((t - 1) & 1) * 8192 + soff);  // h1(t-1)
      u64 y0 = LD_AG(hs1);
      u64 y1 = LD_AG(hs1 + 1);
      u64 y2 = LD_AG(hs1 + 2);
      u64 y3 = LD_AG(hs1 + 3);
      ((u64*)a_x0)[0] = x0; ((u64*)a_x0)[1] = x1;
      ((u64*)a_x1)[0] = x2; ((u64*)a_x1)[1] = x3;
      ((u64*)a_h0)[0] = y0; ((u64*)a_h0)[1] = y1;
      ((u64*)a_h1)[0] = y2; ((u64*)a_h1)[1] = y3;
    }
    __syncthreads();  // B1: A-tile ready

    // fused GEMM K'=1024
    f32x4 acc = (f32x4){0.f, 0.f, 0.f, 0.f};
#pragma unroll
    for (int it = 0; it < 32; ++it)
      acc = MFMA16(lds_a(astage, n15, it, quad), wf[it], acc);
#pragma unroll
    for (int r = 0; r < 4; ++r)
      gbuf[(quad * 4 + r) * 132 + qg * 33 + ch * 16 + n15] = acc[r];
    __syncthreads();  // B2: gbuf ready (astage reads done)

    // elementwise + publish (threads 0-255: b=tid>>4, 2 cols)
    if (tid < 256) {
      const int b = tid >> 4, jc = (tid & 15) * 2;
      float hv[2];
#pragma unroll
      for (int j = 0; j < 2; ++j) {
        const float* gb = gbuf + b * 132 + jc + j;
        float gi = gb[0] + bb[0][j];
        float gf = gb[33] + bb[1][j];
        float gg = gb[66] + bb[2][j];
        float go = gb[99] + bb[3][j];
        float cprev = j ? cs1 : cs0;
        float c = sigf(gf) * cprev + sigf(gi) * tanhf_fast(gg);
        if (j) cs1 = c; else cs0 = c;
        hv[j] = sigf(go) * tanhf_fast(c);
      }
      union { f16 h2[2]; unsigned u; } pk;
      pk.h2[0] = (f16)hv[0];
      pk.h2[1] = (f16)hv[1];
      f16* dst = (l == 0)
          ? h0buf + h0base + (size_t)(t & 3) * 8192 + (size_t)b * 512 + c0 + jc
          : h1buf + h1base + (size_t)(t & 1) * 8192 + (size_t)b * 512 + c0 + jc;
      ST_AG((unsigned*)dst, pk.u);
      if (l == 1 && t == 511) {
        hlast[(size_t)(b0 + b) * 512 + c0 + jc] = hv[0];
        hlast[(size_t)(b0 + b) * 512 + c0 + jc + 1] = hv[1];
      }
    }
    __syncthreads();  // B3: vmcnt drained -> h stores visible
    if (tid == 0) ST_AG(myflag, (unsigned)(t + 1));
  }
}

// =====================================================================
// fc head
// =====================================================================
__global__ __launch_bounds__(512) void k_fc(
    const float* __restrict__ hlast, const float* __restrict__ fc1wT,
    const float* __restrict__ fc1b, const float* __restrict__ fc2w,
    const float* __restrict__ fc2b, float* __restrict__ out) {
  __shared__ float hrow[512];
  __shared__ float red[8];
  const int b = blockIdx.x, tid = threadIdx.x;
  hrow[tid] = hlast[b * 512 + tid];
  __syncthreads();
  float acc = 0.f;
#pragma unroll 8
  for (int k = 0; k < 512; ++k) acc += hrow[k] * fc1wT[k * 512 + tid];
  float h1 = acc + fc1b[tid];
  h1 = h1 > 0.f ? h1 : 0.f;
  float v = h1 * fc2w[tid];
#pragma unroll
  for (int off = 32; off >= 1; off >>= 1) v += __shfl_down(v, off);
  if ((tid & 63) == 0) red[tid >> 6] = v;
  __syncthreads();
  if (tid == 0) {
    float s = 0.f;
#pragma unroll
    for (int w = 0; w < 8; ++w) s += red[w];
    out[b] = s + fc2b[0];
  }
}

// =====================================================================
extern "C" void kernel_launch(void* const* d_in, const int* in_sizes, int n_in,
                              void* d_out, int out_size, void* d_ws, size_t ws_size,
                              hipStream_t stream) {
  if (ws_size < WS_NEEDED) return;  // fail loudly

  const float* x = (const float*)d_in[0];
  const float* theta = (const float*)d_in[1];
  const float* phi = (const float*)d_in[2];
  const float* thn = (const float*)d_in[3];
  const float* phn = (const float*)d_in[4];
  const float* Wih = (const float*)d_in[5];
  const float* Whh = (const float*)d_in[6];
  const float* bih = (const float*)d_in[7];
  const float* bhh = (const float*)d_in[8];
  const float* fc1w = (const float*)d_in[9];
  const float* fc1b = (const float*)d_in[10];
  const float* fc2w = (const float*)d_in[11];
  const float* fc2b = (const float*)d_in[12];

  char* ws = (char*)d_ws;
  f16* q16 = (f16*)(ws + OFF_Q16);
  f16* x16 = (f16*)(ws + OFF_X16);
  f16* w16 = (f16*)(ws + OFF_W16);
  f16* cosT = (f16*)(ws + OFF_COS);
  f16* sinT = (f16*)(ws + OFF_SIN);
  float* bsum = (float*)(ws + OFF_BSUM);
  f16* h0buf = (f16*)(ws + OFF_HBUF);
  f16* h1buf = h0buf + 131072;  // +262,144 B
  float* hlast = (float*)(ws + OFF_HLAST);
  float* fc1wT = (float*)(ws + OFF_FC1WT);
  unsigned* flg = (unsigned*)(ws + OFF_FLG);

  k_prep<<<2048, 256, 0, stream>>>(x, theta, phi, thn, phn, Wih, Whh, bih, bhh, fc1w,
                                   x16, w16, cosT, sinT, bsum, fc1wT, h0buf, flg);
  k_quantum<<<dim3(512, 4, 1), 256, 0, stream>>>(x16, cosT, sinT, q16);
  k_rec<<<128, 512, 0, stream>>>(q16, w16, bsum, h0buf, h1buf, hlast, flg);
  k_fc<<<64, 512, 0, stream>>>(hlast, fc1wT, fc1b, fc2w, fc2b, (float*)d_out);
}